// Round 7
// baseline (20.554 us; speedup 1.0000x reference)
//
#include <hip/hip_runtime.h>

typedef unsigned long long u64;
typedef unsigned int u32;

#define W    4096
#define NLANE 64
#define D32  32

// argmax over kb[64] with left preference (smaller k wins ties) --
// exactly reproduces u64 key (abs desc, pos asc) ordering.
#define EXTRACT()                                                        \
  do {                                                                   \
    u64 best = 0ull;                                                     \
    _Pragma("unroll")                                                    \
    for (int g8 = 0; g8 < 8; ++g8) {                                     \
      u64 b = ((u64)kb[8 * g8] << 32) | (u64)(63 - 8 * g8);              \
      _Pragma("unroll")                                                  \
      for (int k8 = 1; k8 < 8; ++k8) {                                   \
        const u64 n = ((u64)kb[8 * g8 + k8] << 32) | (u64)(63 - (8 * g8 + k8)); \
        if (n > b) b = n;                                                \
      }                                                                  \
      if (b > best) best = b;                                            \
    }                                                                    \
    M = (u32)(best >> 32);                                               \
    o = 63 - (int)(best & 63ull);                                        \
  } while (0)

__global__ __launch_bounds__(NLANE) void extrema_nms_wave(
    const float* __restrict__ x,
    const int*   __restrict__ dist_p,
    float*       __restrict__ out)
{
    const int sig  = blockIdx.x;
    const int lane = threadIdx.x;            // 0..63, one wave
    const float* xg = x + (size_t)sig * W;
    float*       og = out + (size_t)sig * W;
    const int dist = *dist_p;

    __shared__ u64 key[W];                   // generic fallback only (32 KB)

    if (dist == D32) {
        // ---------- 1-wave fast path: lane l owns elements [64l, 64l+64) ----------
        float f[64];
        {
            const float4* xg4 = (const float4*)xg + lane * 16;
            #pragma unroll
            for (int v = 0; v < 16; ++v) {
                const float4 q = xg4[v];
                f[4 * v] = q.x; f[4 * v + 1] = q.y; f[4 * v + 2] = q.z; f[4 * v + 3] = q.w;
            }
        }
        float fl = __shfl_up(f[63], 1);      // x[64l - 1]
        if (lane == 0) fl = __int_as_float(0x7f800000);  // +inf -> left=true at i=0
        float fr = __shfl_down(f[0], 1);     // x[64l + 64]
        if (lane == NLANE - 1) fr = f[63];   // x==x -> right=false at i=W-1

        // extrema keys: kb = (abs_bits<<1)|1 if extremum else 0 (0 = dead)
        u32 kb[64];
        #pragma unroll
        for (int k = 0; k < 64; ++k) {
            const float xi = f[k];
            const float xn = (k < 63) ? f[k + 1] : fr;
            const float xp = (k > 0)  ? f[k - 1] : fl;
            const bool right = xn > xi;       // pad-right -> false
            const bool left  = xi <= xp;      // pad-left  -> true
            const bool s     = xi <= 0.0f;
            const bool ext = (right && left && s) || (!right && !left && !s);
            const u32 ab = __float_as_uint(xi) & 0x7fffffffu;
            kb[k] = ext ? ((ab << 1) | 1u) : 0u;
        }

        u64 keepmask = 0ull;
        u32 M; int o;                        // own chunk candidate (key, offset)
        EXTRACT();

        for (;;) {
            if (__ballot(M != 0u) == 0ull) break;   // uniform: all chunks dead

            // exchange candidates with neighbor chunks
            u32 ML = __shfl_up(M, 1);  int oL = __shfl_up(o, 1);
            u32 MR = __shfl_down(M, 1); int oR = __shfl_down(o, 1);
            if (lane == 0)         ML = 0;
            if (lane == NLANE - 1) MR = 0;

            // push-kill: do my live elements suppress neighbor candidates?
            // left candidate has smaller pos -> strict >; right -> >= (tie = my priority)
            int killL = 0;
            if (ML != 0u && M > ML && oL >= 32) {
                const int hi = oL - 32;            // k in [0, hi], hi <= 31
                #pragma unroll
                for (int k = 0; k < 32; ++k)
                    killL |= (int)((k <= hi) & (kb[k] > ML));
            }
            int killR = 0;
            if (MR != 0u && M >= MR && oR <= 31) {
                const int lo = oR + 32;            // k in [lo, 63], lo >= 32
                #pragma unroll
                for (int k = 32; k < 64; ++k)
                    killR |= (int)((k >= lo) & (kb[k] >= MR));
            }
            // route killbits to candidate owners
            int kdL = __shfl_up(killR, 1);   // lane-1's killR targets my chunk
            int kdR = __shfl_down(killL, 1); // lane+1's killL targets my chunk
            if (lane == 0)         kdL = 0;
            if (lane == NLANE - 1) kdR = 0;

            const bool keep = (M != 0u) && !kdL && !kdR;

            // neighbors' keeper status
            int keepL = __shfl_up((int)keep, 1);
            int keepR = __shfl_down((int)keep, 1);
            if (lane == 0)         keepL = 0;
            if (lane == NLANE - 1) keepR = 0;

            // dead window mask over my 64 elements
            u64 dead = 0ull;
            if (keep) {
                keepmask |= (1ull << o);
                const int lo = (o - 32 < 0) ? 0 : o - 32;
                const int hi = (o + 32 > 63) ? 63 : o + 32;
                dead |= (~0ull >> (63 - hi)) & (~0ull << lo);
            }
            if (keepL && oL >= 32) dead |= (~0ull >> (63 - (oL - 32)));  // [0, oL-32]
            if (keepR && oR <= 31) dead |= (~0ull << (oR + 32));         // [oR+32, 63]

            if (dead != 0ull) {
                const u32 dl = (u32)dead, dh = (u32)(dead >> 32);
                #pragma unroll
                for (int k = 0; k < 32; ++k)
                    if ((dl >> k) & 1u) kb[k] = 0u;
                #pragma unroll
                for (int k = 32; k < 64; ++k)
                    if ((dh >> (k - 32)) & 1u) kb[k] = 0u;
                if (M != 0u && ((dead >> o) & 1ull)) EXTRACT();  // argmax died -> rescan
            }
        }

        // output: reload x (L2-hot) and select kept positions
        {
            const float4* xg4 = (const float4*)xg + lane * 16;
            float4*       og4 = (float4*)og + lane * 16;
            #pragma unroll
            for (int v = 0; v < 16; ++v) {
                const float4 q = xg4[v];
                float4 oq;
                oq.x = ((keepmask >> (4 * v))     & 1ull) ? q.x : 0.0f;
                oq.y = ((keepmask >> (4 * v + 1)) & 1ull) ? q.y : 0.0f;
                oq.z = ((keepmask >> (4 * v + 2)) & 1ull) ? q.z : 0.0f;
                oq.w = ((keepmask >> (4 * v + 3)) & 1ull) ? q.w : 0.0f;
                og4[v] = oq;
            }
        }
    } else {
        // ---------- generic fallback (any dist): serial greedy, 1 wave ----------
        for (int i = lane; i < W; i += NLANE) og[i] = 0.0f;
        for (int i = lane; i < W; i += NLANE) {
            const float xi = xg[i];
            const bool right = (i < W - 1) ? (xg[i + 1] > xi) : false;
            const bool left  = (i > 0)     ? (xi <= xg[i - 1]) : true;
            const bool s = (xi <= 0.0f);
            const bool valley = right && left && s;
            const bool peak   = !right && !left && !s;
            const u32 ab = __float_as_uint(xi) & 0x7fffffffu;
            key[i] = (valley || peak) ? (((u64)ab << 32) | (u64)(u32)(W - 1 - i)) : 0ull;
        }
        __syncthreads();

        for (;;) {
            u64 m = 0ull;
            for (int j = lane; j < W; j += NLANE) {
                const u64 k = key[j];
                if (k > m) m = k;
            }
            #pragma unroll
            for (int off = 32; off > 0; off >>= 1) {
                const u64 t = __shfl_down(m, off, 64);
                if (t > m) m = t;
            }
            m = __shfl(m, 0, 64);
            if (m == 0ull) break;

            const int p = (W - 1) - (int)(m & 0xffffffffu);
            if (lane == 0) og[p] = xg[p];

            int lo = p - dist; lo = lo < 0 ? 0 : lo;
            int hi = p + dist; hi = hi > (W - 1) ? (W - 1) : hi;
            for (int j = lo + lane; j <= hi; j += NLANE) key[j] = 0ull;
            __syncthreads();
        }
    }
}

extern "C" void kernel_launch(void* const* d_in, const int* in_sizes, int n_in,
                              void* d_out, int out_size, void* d_ws, size_t ws_size,
                              hipStream_t stream) {
    const float* x      = (const float*)d_in[0];
    const int*   dist_p = (const int*)d_in[1];
    float*       out    = (float*)d_out;
    const int nsig = in_sizes[0] / W;   // 128 signals of length 4096
    hipLaunchKernelGGL(extrema_nms_wave, dim3(nsig), dim3(NLANE), 0, stream,
                       x, dist_p, out);
}